// Round 1
// baseline (231.911 us; speedup 1.0000x reference)
//
#include <hip/hip_runtime.h>
#include <math.h>

// Capsule routing, restructured to avoid materializing u_hat (537 MB).
// o[b,n,:] = W_n * (sum_i c[b,n,i] u[b,i,:]) ;  b[b,n,i] = u[b,i,:] . (W_n^T o_n)
// All fp32. Workspace usage: t(2MB) + bl(8MB) + sp(16MB) + sp0(0.5MB) = 26.6 MB.

#define B   64
#define IN  1024
#define ID  256
#define NC  32
#define DC  64

// ---------------------------------------------------------------------------
// sp0[c][b][d] = sum over i-chunk c of u[b][i][d]   (8 chunks of 128 i)
__global__ __launch_bounds__(256) void k_sumu(const float* __restrict__ u,
                                              float* __restrict__ sp0) {
    const int c = blockIdx.x, b = blockIdx.y;
    const int d = threadIdx.x;
    const float* up = u + ((size_t)b * IN + (size_t)c * (IN / 8)) * ID + d;
    float acc = 0.f;
#pragma unroll 8
    for (int i = 0; i < IN / 8; ++i) acc += up[(size_t)i * ID];
    sp0[(c * B + b) * ID + d] = acc;
}

// ---------------------------------------------------------------------------
// Per (b,n): s = (reduced partials); o = W_n s ; then
//   mode 0: s from sp0 (uniform c=1/32), normalize o, t = W_n^T o_norm
//   mode 1: s from sp,                  normalize o, t = W_n^T o_norm
//   mode 2: s from sp, squash(o) -> out
__global__ __launch_bounds__(256) void k_ot(const float* __restrict__ W,
                                            const float* __restrict__ src,
                                            float* __restrict__ tout,
                                            const int mode) {
    const int bn = blockIdx.x;
    const int b = bn / NC, n = bn % NC;
    __shared__ float s_lds[ID];
    __shared__ float o_lds[DC];
    __shared__ float on_lds[DC];
    const int tid = threadIdx.x;

    // reduce partial sums into s_lds
    float sv = 0.f;
    if (mode == 0) {
#pragma unroll
        for (int c = 0; c < 8; ++c) sv += src[(c * B + b) * ID + tid];
        sv *= (1.0f / NC);
    } else {
#pragma unroll
        for (int c = 0; c < 8; ++c) sv += src[((size_t)(c * B + b) * NC + n) * ID + tid];
    }
    s_lds[tid] = sv;
    __syncthreads();

    // o[d] = dot(W[n*DC+d, :], s)   — wave per row, 16 rows per wave
    const int wave = tid >> 6, lane = tid & 63;
    const float* Wn = W + (size_t)n * DC * ID;
#pragma unroll 4
    for (int r = 0; r < 16; ++r) {
        const int d = wave * 16 + r;
        const float* wrow = Wn + (size_t)d * ID;
        float p = wrow[lane]        * s_lds[lane]
                + wrow[lane + 64]   * s_lds[lane + 64]
                + wrow[lane + 128]  * s_lds[lane + 128]
                + wrow[lane + 192]  * s_lds[lane + 192];
#pragma unroll
        for (int off = 32; off > 0; off >>= 1) p += __shfl_down(p, off);
        if (lane == 0) o_lds[d] = p;
    }
    __syncthreads();

    if (mode == 2) {
        if (tid < DC) {
            float v = o_lds[tid];
            float sq = v * v;
#pragma unroll
            for (int off = 32; off > 0; off >>= 1) sq += __shfl_down(sq, off);
            sq = __shfl(sq, 0) + 1e-7f;
            const float sc = sqrtf(sq) / (0.5f + sq);
            tout[(size_t)(b * NC + n) * DC + tid] = v * sc;
        }
        return;
    }

    // normalize o (F.normalize: x / max(||x||, 1e-12))
    if (tid < DC) {
        float v = o_lds[tid];
        float sq = v * v;
#pragma unroll
        for (int off = 32; off > 0; off >>= 1) sq += __shfl_down(sq, off);
        sq = __shfl(sq, 0);
        const float inv = 1.0f / fmaxf(sqrtf(sq), 1e-12f);
        on_lds[tid] = v * inv;
    }
    __syncthreads();

    // t[k] = sum_d W[n*DC+d, k] * on[d]   — thread per k, coalesced column walk
    float acc = 0.f;
    const float* wc = Wn + tid;
#pragma unroll 8
    for (int d = 0; d < DC; ++d) acc += wc[(size_t)d * ID] * on_lds[d];
    tout[((size_t)b * NC + n) * ID + tid] = acc;
}

// ---------------------------------------------------------------------------
// bl[b][i][n] = sum_d u[b][i][d] * t[b][n][d]
// Block: one batch, 128-i tile x 32 n, K=256 in chunks of 16.
#define ITILE 128
__global__ __launch_bounds__(256) void k_bl(const float* __restrict__ u,
                                            const float* __restrict__ t,
                                            float* __restrict__ bl) {
    const int it = blockIdx.x, b = blockIdx.y;
    const int iBase = it * ITILE;
    __shared__ float Ts[ID][36];     // t[b] transposed: Ts[k][n], pad->36 (16B-aligned f4)
    __shared__ float Us[16][132];    // u chunk transposed: Us[k][i], pad->132
    const int tid = threadIdx.x;

    // load full Ts (one-time): thread=k, loop n. Global coalesced.
    {
        const float* tb = t + (size_t)b * NC * ID;
#pragma unroll
        for (int n = 0; n < NC; ++n) Ts[tid][n] = tb[(size_t)n * ID + tid];
    }

    const int q = tid >> 3;   // i-thread: i0 = q*4
    const int r = tid & 7;    // n-thread: n0 = r*4
    float acc[4][4] = {{0.f}};
    const float* ub = u + ((size_t)b * IN + iBase) * ID;

    for (int kc = 0; kc < ID / 16; ++kc) {
        __syncthreads();   // Ts ready (first iter) / prior chunk consumed
        // stage 128 i x 16 k, transposed. 512 float4 loads, 2 per thread.
#pragma unroll
        for (int rep = 0; rep < 2; ++rep) {
            const int f = tid + rep * 256;
            const int i = f >> 2, c4 = f & 3;
            const float4 v = *(const float4*)(ub + (size_t)i * ID + kc * 16 + c4 * 4);
            Us[c4 * 4 + 0][i] = v.x;
            Us[c4 * 4 + 1][i] = v.y;
            Us[c4 * 4 + 2][i] = v.z;
            Us[c4 * 4 + 3][i] = v.w;
        }
        __syncthreads();
#pragma unroll
        for (int k = 0; k < 16; ++k) {
            const float4 a4 = *(const float4*)&Us[k][q * 4];
            const float4 b4 = *(const float4*)&Ts[kc * 16 + k][r * 4];
            const float av[4] = {a4.x, a4.y, a4.z, a4.w};
            const float bv[4] = {b4.x, b4.y, b4.z, b4.w};
#pragma unroll
            for (int ii = 0; ii < 4; ++ii)
#pragma unroll
                for (int jj = 0; jj < 4; ++jj) acc[ii][jj] += av[ii] * bv[jj];
        }
    }

    float* blb = bl + ((size_t)b * IN + iBase) * NC;
#pragma unroll
    for (int ii = 0; ii < 4; ++ii) {
        const float4 v = make_float4(acc[ii][0], acc[ii][1], acc[ii][2], acc[ii][3]);
        *(float4*)&blb[(size_t)(q * 4 + ii) * NC + r * 4] = v;
    }
}

// ---------------------------------------------------------------------------
// c = softmax_n(bl[b,i,:]) ; sp[c][b][n][d] = sum_{i in chunk} c[n] * u[b,i,d]
#define AITILE 128
__global__ __launch_bounds__(256) void k_agg(const float* __restrict__ u,
                                             const float* __restrict__ bl,
                                             float* __restrict__ sp) {
    const int c = blockIdx.x, b = blockIdx.y;   // 8 chunks of 128 i
    const int iBase = c * AITILE;
    __shared__ float c_lds[AITILE][36];
    const int tid = threadIdx.x;

    // phase A: softmax over 32 contiguous logits; 2 threads per i (16 n each)
    {
        const int i = tid >> 1, half = tid & 1;
        const float* blp = bl + ((size_t)b * IN + iBase + i) * NC + half * 16;
        float v[16];
#pragma unroll
        for (int j = 0; j < 16; ++j) v[j] = blp[j];
        float mx = v[0];
#pragma unroll
        for (int j = 1; j < 16; ++j) mx = fmaxf(mx, v[j]);
        mx = fmaxf(mx, __shfl_xor(mx, 1));
        float sum = 0.f;
#pragma unroll
        for (int j = 0; j < 16; ++j) { v[j] = __expf(v[j] - mx); sum += v[j]; }
        sum += __shfl_xor(sum, 1);
        const float inv = 1.0f / sum;
#pragma unroll
        for (int j = 0; j < 16; ++j) c_lds[i][half * 16 + j] = v[j] * inv;
    }
    __syncthreads();

    // phase B: thread owns 4 d (float4) x 8 n -> 32 accumulators
    const int d4 = tid & 63;       // float4 index into ID
    const int ng = tid >> 6;       // n base = ng*8 (wave-uniform -> LDS broadcast)
    float acc[8][4] = {{0.f}};
    const float* ub = u + ((size_t)b * IN + iBase) * ID + d4 * 4;
    for (int i = 0; i < AITILE; ++i) {
        const float4 uv = *(const float4*)(ub + (size_t)i * ID);
        const float4 c0 = *(const float4*)&c_lds[i][ng * 8];
        const float4 c1 = *(const float4*)&c_lds[i][ng * 8 + 4];
        const float cv[8] = {c0.x, c0.y, c0.z, c0.w, c1.x, c1.y, c1.z, c1.w};
        const float uvv[4] = {uv.x, uv.y, uv.z, uv.w};
#pragma unroll
        for (int j = 0; j < 8; ++j)
#pragma unroll
            for (int x = 0; x < 4; ++x) acc[j][x] += cv[j] * uvv[x];
    }

    float* spb = sp + (size_t)(c * B + b) * NC * ID;
#pragma unroll
    for (int j = 0; j < 8; ++j) {
        const int n = ng * 8 + j;
        *(float4*)&spb[(size_t)n * ID + d4 * 4] =
            make_float4(acc[j][0], acc[j][1], acc[j][2], acc[j][3]);
    }
}

// ---------------------------------------------------------------------------
extern "C" void kernel_launch(void* const* d_in, const int* in_sizes, int n_in,
                              void* d_out, int out_size, void* d_ws, size_t ws_size,
                              hipStream_t stream) {
    const float* u = (const float*)d_in[0];   // [B][IN][ID]
    const float* W = (const float*)d_in[1];   // [NC*DC][ID]
    float* out = (float*)d_out;               // [B][NC][DC]

    float* ws  = (float*)d_ws;
    float* t   = ws;                                   // B*NC*ID      = 0.5M floats
    float* bl  = t  + (size_t)B * NC * ID;             // B*IN*NC      = 2M floats
    float* sp  = bl + (size_t)B * IN * NC;             // 8*B*NC*ID    = 4M floats
    float* sp0 = sp + (size_t)8 * B * NC * ID;         // 8*B*ID       = 128K floats

    const dim3 blk(256);

    // routing iteration 0 (c uniform = 1/32)
    k_sumu<<<dim3(8, B), blk, 0, stream>>>(u, sp0);
    k_ot  <<<dim3(B * NC), blk, 0, stream>>>(W, sp0, t, 0);
    // iteration 1
    k_bl  <<<dim3(IN / ITILE, B), blk, 0, stream>>>(u, t, bl);
    k_agg <<<dim3(IN / AITILE, B), blk, 0, stream>>>(u, bl, sp);
    k_ot  <<<dim3(B * NC), blk, 0, stream>>>(W, sp, t, 1);
    // iteration 2
    k_bl  <<<dim3(IN / ITILE, B), blk, 0, stream>>>(u, t, bl);
    k_agg <<<dim3(IN / AITILE, B), blk, 0, stream>>>(u, bl, sp);
    k_ot  <<<dim3(B * NC), blk, 0, stream>>>(W, sp, out, 2);
}